// Round 14
// baseline (154.015 us; speedup 1.0000x reference)
//
#include <hip/hip_runtime.h>

#define NW    16
#define NEUR  128
#define NPTS  65536
#define SIGMA 0.02f
#define U_MEAN 0.0f
#define U_SD   1.0f
#define DELTA 0.19f          // cull radius (measured: absmax unchanged vs no-cull)

#define TILE   64           // points per block (4 waves x 16 rows)
#define NTHR   256
#define HPAD   136          // h2 row stride: 272B, 16B-aligned (R2: 132 -> misaligned-b128 replay)
#define MAT_HALVES 16384                  // frag-linear fp16 matrix: 128x128 (R10-verified layout)
#define WT_HALVES (2*NW*MAT_HALVES)       // 1,048,576 B
#define WT_BYTES (WT_HALVES*2)
#define CNT_OFF  WT_BYTES                 // 256 ints
#define IDX_OFF  (WT_BYTES + 1024)        // segmented u16 lists, 1 MB
#define NSEG   16
#define SEGPTS (NPTS/NSEG)
#define CAPSEG 2048                       // max fill ~1910
#define CHUNKS 512                        // 16*2048/64

typedef _Float16 half8 __attribute__((ext_vector_type(8)));
typedef float    f32x4 __attribute__((ext_vector_type(4)));

typedef const __attribute__((address_space(1))) void* gptr_t;
typedef       __attribute__((address_space(3))) void* lptr_t;

// Paired tanh: ONE v_rcp serves two evaluations (1/a0 = rcp(a0a1)*a1).
// Trans ops per tanh: 2 -> 1.5 (trans pipe is the measured bottleneck, R13).
// Clamp 2x <= 42: a <= 1.7e18, product <= 3e36 finite; tanh(21) == 1.0f exact.
__device__ __forceinline__ void tanh2(float x0, float x1, float& y0, float& y1) {
    float a0 = 1.0f + __expf(fminf(x0 + x0, 42.0f));
    float a1 = 1.0f + __expf(fminf(x1 + x1, 42.0f));
    float rp = __builtin_amdgcn_rcpf(a0 * a1);
    y0 = fmaf(-2.0f * a1, rp, 1.0f);   // 1 - 2/a0
    y1 = fmaf(-2.0f * a0, rp, 1.0f);   // 1 - 2/a1
}

// ONE aux dispatch (R10's frag-linear prep, correctness-verified R10/R12/R13):
//   wt half offset = (s*8+c)*512 + lane*8 + j  holding W[e=c*16+m][d=s*32+q*8+j], lane=q*16+m
//   [0,32) prep | [32,288) bucket | [288,320) zero out[]
__global__ __launch_bounds__(512) void aux_kernel(
    const float* __restrict__ W_hid, const float* __restrict__ x,
    const float* __restrict__ mids,  _Float16* __restrict__ wt,
    int* __restrict__ cnt16, unsigned short* __restrict__ idx,
    float* __restrict__ out)
{
    const int b = blockIdx.x;
    const int t = threadIdx.x;

    if (b < 32) {                          // ---- prep: one 128x128 matrix per block
        __shared__ __align__(16) _Float16 tile[NEUR * HPAD];   // transpose staging
        const int lw = b;
        const float4* src = (const float4*)(W_hid + (size_t)lw * NEUR * NEUR);
#pragma unroll
        for (int it = 0; it < 8; ++it) {   // 4096 float4, coalesced over e
            int f4 = it * 512 + t;
            int d  = f4 >> 5;
            int e0 = (f4 & 31) << 2;
            float4 v = src[f4];
            tile[(e0 + 0) * HPAD + d] = (_Float16)v.x;
            tile[(e0 + 1) * HPAD + d] = (_Float16)v.y;
            tile[(e0 + 2) * HPAD + d] = (_Float16)v.z;
            tile[(e0 + 3) * HPAD + d] = (_Float16)v.w;
        }
        __syncthreads();
        half8* dst8 = (half8*)(wt + (size_t)lw * MAT_HALVES);  // 2048 half8 chunks
#pragma unroll
        for (int it = 0; it < 4; ++it) {
            int h8 = it * 512 + t;
            int sc = h8 >> 6;              // s*8+c
            int ln = h8 & 63;              // lane = q*16+m
            int s_ = sc >> 3, c_ = sc & 7;
            int q_ = ln >> 4, m_ = ln & 15;
            dst8[h8] = *(const half8*)&tile[(c_ * 16 + m_) * HPAD + s_ * 32 + q_ * 8];
        }
    } else if (b < 288) {                  // ---- bucket: (segment, window)
        const int s = (b - 32) & (NSEG - 1);
        const int w = (b - 32) >> 4;
        __shared__ int lcnt;
        if (t == 0) lcnt = 0;
        __syncthreads();
        const float lo = mids[w] - DELTA;
        const float hi = mids[w + 1] + DELTA;
        const int lane = t & 63;
        unsigned short* dst = idx + (size_t)(w * NSEG + s) * CAPSEG;
#pragma unroll
        for (int it = 0; it < SEGPTS / 512; ++it) {
            int i = s * SEGPTS + it * 512 + t;
            float xv = x[i];
            bool need = (xv >= lo) && (xv <= hi);
            unsigned long long mask = __ballot(need);
            if (mask) {
                int leader = (int)__builtin_ctzll(mask);
                int total  = (int)__popcll(mask);
                int rank   = (int)__popcll(mask & ((1ull << lane) - 1ull));
                int base = 0;
                if (lane == leader) base = atomicAdd(&lcnt, total);   // LDS atomic
                base = __shfl(base, leader);
                int slot = base + rank;
                if (need && slot < CAPSEG) dst[slot] = (unsigned short)i;
            }
        }
        __syncthreads();
        if (t == 0) cnt16[w * NSEG + s] = lcnt;
    } else {                               // ---- zero out[]
        int i4 = (b - 288) * 512 + t;
        float4 z = {0.f, 0.f, 0.f, 0.f};
        ((float4*)out)[i4] = z;
    }
}

__global__ __launch_bounds__(NTHR, 3) void fbpinn_main(
    const float* __restrict__ x,     const float* __restrict__ means,
    const float* __restrict__ stds,  const float* __restrict__ mids,
    const float* __restrict__ W_in,  const float* __restrict__ b_in,
    const float* __restrict__ b_hid, const float* __restrict__ W_out,
    const float* __restrict__ b_out, const _Float16* __restrict__ wt,
    const int* __restrict__ cnt16,   const unsigned short* __restrict__ idx,
    float* __restrict__ out)
{
    const int w    = blockIdx.y;
    const int base = blockIdx.x * TILE;

    // uniform scan of cnt16 (scalar loads); uniform exit
    int csh[NSEG];
    int total = 0;
#pragma unroll
    for (int k = 0; k < NSEG; ++k) {
        int c = cnt16[w * NSEG + k];
        c = c > CAPSEG ? CAPSEG : c;
        csh[k] = c;
        total += c;
    }
    if (base >= total) return;
    const int nvalid = min(TILE, total - base);

    __shared__ __align__(16) _Float16 Wb[MAT_HALVES];    // 32768 B, frag-linear (W0 then W1)
    __shared__ __align__(16) _Float16 Hl[TILE * HPAD];   // 17408 B (h2)

    const int t    = threadIdx.x;
    const int lane = t & 63;
    const int wave = t >> 6;           // 0..3
    const int m    = lane & 15;
    const int q    = lane >> 4;
    const int row0 = wave * 16;
    const int rsel = m & 3;

    // stage W0 via direct global->LDS (no VGPR round-trip — R12's register
    // prefetch spilled 207 MB to scratch)
    {
        const char* gb = (const char*)(wt + (size_t)(0 * NW + w) * MAT_HALVES) + t * 16;
        char*       lb = (char*)Wb + wave * 64 * 16;
#pragma unroll
        for (int i = 0; i < 8; ++i)
            __builtin_amdgcn_global_load_lds((gptr_t)(gb + i * 4096), (lptr_t)(lb + i * 4096), 16, 0, 0);
    }

    // per-thread gather of own point (row0+m); true-running-prefix scan (R7 fix)
    int v = base + min(row0 + m, nvalid - 1);
    int seg = 0, segbase = 0, pre = 0;
#pragma unroll
    for (int k = 0; k < NSEG - 1; ++k) {
        pre += csh[k];
        if (v >= pre) { seg = k + 1; segbase = pre; }
    }
    const int   gi = idx[(size_t)(w * NSEG + seg) * CAPSEG + (v - segbase)];
    const float xv = x[gi];

    // L0 into GEMM1 A-fragments (pre-barrier: depends only on own xv); paired tanh
    const float xn = (xv - means[w]) * __builtin_amdgcn_rcpf(stds[w]);
    const float* win = W_in + w * NEUR;
    const float* bin = b_in + w * NEUR;
    half8 af[4];
#pragma unroll
    for (int s = 0; s < 4; ++s) {
        const int n0 = s * 32 + q * 8;
        float4 wv0 = *(const float4*)&win[n0];
        float4 wv1 = *(const float4*)&win[n0 + 4];
        float4 bv0 = *(const float4*)&bin[n0];
        float4 bv1 = *(const float4*)&bin[n0 + 4];
        float y0, y1;
        tanh2(fmaf(xn, wv0.x, bv0.x), fmaf(xn, wv0.y, bv0.y), y0, y1);
        af[s][0] = (_Float16)y0; af[s][1] = (_Float16)y1;
        tanh2(fmaf(xn, wv0.z, bv0.z), fmaf(xn, wv0.w, bv0.w), y0, y1);
        af[s][2] = (_Float16)y0; af[s][3] = (_Float16)y1;
        tanh2(fmaf(xn, wv1.x, bv1.x), fmaf(xn, wv1.y, bv1.y), y0, y1);
        af[s][4] = (_Float16)y0; af[s][5] = (_Float16)y1;
        tanh2(fmaf(xn, wv1.z, bv1.z), fmaf(xn, wv1.w, bv1.w), y0, y1);
        af[s][6] = (_Float16)y0; af[s][7] = (_Float16)y1;
    }
    __syncthreads();   // barrier 1: W0 landed (vmcnt drained) + visible

    // GEMM1: B-frag (s,c) = contiguous 1 KB at Wb[(s*8+c)*512 halves]
    const half8* B = (const half8*)Wb;
    f32x4 acc[8];
    const f32x4 zz = {0.f, 0.f, 0.f, 0.f};
#pragma unroll
    for (int c = 0; c < 8; ++c) acc[c] = zz;
#pragma unroll
    for (int s = 0; s < 4; ++s)
#pragma unroll
        for (int c = 0; c < 8; ++c)
            acc[c] = __builtin_amdgcn_mfma_f32_16x16x32_f16(af[s], B[(s * 8 + c) * 64 + lane], acc[c], 0, 0, 0);

    __syncthreads();   // barrier 2: all waves done reading W0

    // issue W1 global->LDS now; latency hides under the h2-tanh block below
    {
        const char* gb = (const char*)(wt + (size_t)(1 * NW + w) * MAT_HALVES) + t * 16;
        char*       lb = (char*)Wb + wave * 64 * 16;
#pragma unroll
        for (int i = 0; i < 8; ++i)
            __builtin_amdgcn_global_load_lds((gptr_t)(gb + i * 4096), (lptr_t)(lb + i * 4096), 16, 0, 0);
    }

    // h2 = tanh(z2+b) -> Hl own rows (same-wave dep for GEMM2 A-reads); paired tanh
    {
        const float* bh0 = b_hid + (0 * NW + w) * NEUR;
#pragma unroll
        for (int c = 0; c < 8; ++c) {
            float bb = bh0[c * 16 + m];
            float y0, y1, y2, y3;
            tanh2(acc[c][0] + bb, acc[c][1] + bb, y0, y1);
            tanh2(acc[c][2] + bb, acc[c][3] + bb, y2, y3);
            Hl[(row0 + q * 4 + 0) * HPAD + c * 16 + m] = (_Float16)y0;
            Hl[(row0 + q * 4 + 1) * HPAD + c * 16 + m] = (_Float16)y1;
            Hl[(row0 + q * 4 + 2) * HPAD + c * 16 + m] = (_Float16)y2;
            Hl[(row0 + q * 4 + 3) * HPAD + c * 16 + m] = (_Float16)y3;
        }
    }
    __syncthreads();   // barrier 3: W1 landed (vmcnt drained) + visible

    // GEMM2: A from own 16 rows of Hl, B frag-linear from Wb
#pragma unroll
    for (int c = 0; c < 8; ++c) acc[c] = zz;
#pragma unroll
    for (int s = 0; s < 4; ++s) {
        half8 a = *(const half8*)(Hl + (row0 + m) * HPAD + s * 32 + q * 8);
#pragma unroll
        for (int c = 0; c < 8; ++c)
            acc[c] = __builtin_amdgcn_mfma_f32_16x16x32_f16(a, B[(s * 8 + c) * 64 + lane], acc[c], 0, 0, 0);
    }

    // epilogue: h3 = tanh(z3+b) (paired); dot W_out; reduce over 16 m-lanes
    const float* bh1 = b_hid + (1 * NW + w) * NEUR;
    const float* wo  = W_out + w * NEUR;
    float t0 = 0.f, t1 = 0.f, t2 = 0.f, t3 = 0.f;
#pragma unroll
    for (int c = 0; c < 8; ++c) {
        float b  = bh1[c * 16 + m];
        float wc = wo[c * 16 + m];
        float y0, y1, y2, y3;
        tanh2(acc[c][0] + b, acc[c][1] + b, y0, y1);
        tanh2(acc[c][2] + b, acc[c][3] + b, y2, y3);
        t0 = fmaf(y0, wc, t0);
        t1 = fmaf(y1, wc, t1);
        t2 = fmaf(y2, wc, t2);
        t3 = fmaf(y3, wc, t3);
    }
    t0 += __shfl_xor(t0, 1); t1 += __shfl_xor(t1, 1);
    t2 += __shfl_xor(t2, 1); t3 += __shfl_xor(t3, 1);
    t0 += __shfl_xor(t0, 2); t1 += __shfl_xor(t1, 2);
    t2 += __shfl_xor(t2, 2); t3 += __shfl_xor(t3, 2);
    float vsum = (rsel == 0) ? t0 : (rsel == 1) ? t1 : (rsel == 2) ? t2 : t3;
    vsum += __shfl_xor(vsum, 4);
    vsum += __shfl_xor(vsum, 8);

    // point data for slot = row0 + q*4 + rsel lives at lane 20*q + rsel (R12-verified)
    const int   slot  = row0 + q * 4 + rsel;
    const float xslot = __shfl(xv, 20 * q + rsel);
    const int   gslot = __shfl(gi, 20 * q + rsel);
    if (m < 4 && slot < nvalid) {
        float u  = (vsum + b_out[w]) * U_SD + U_MEAN;
        float xl = (xslot - mids[w])     * (1.0f / SIGMA);
        float xr = (xslot - mids[w + 1]) * (1.0f / SIGMA);
        // wf = sigmoid(-xl)*sigmoid(xr) = 1/((1+e^xl)(1+e^-xr)); one rcp
        float a0 = 1.0f + __expf(xl);
        float a1 = 1.0f + __expf(-xr);
        float wf = __builtin_amdgcn_rcpf(a0 * a1);
        atomicAdd(&out[gslot], wf * u);
    }
}

extern "C" void kernel_launch(void* const* d_in, const int* in_sizes, int n_in,
                              void* d_out, int out_size, void* d_ws, size_t ws_size,
                              hipStream_t stream) {
    const float* x     = (const float*)d_in[0];
    const float* means = (const float*)d_in[1];
    const float* stds  = (const float*)d_in[2];
    const float* mids  = (const float*)d_in[3];
    const float* W_in  = (const float*)d_in[4];
    const float* b_in  = (const float*)d_in[5];
    const float* W_hid = (const float*)d_in[6];
    const float* b_hid = (const float*)d_in[7];
    const float* W_out = (const float*)d_in[8];
    const float* b_out = (const float*)d_in[9];
    float* out = (float*)d_out;

    _Float16*       wt    = (_Float16*)d_ws;                          // 1,048,576 B
    int*            cnt16 = (int*)((char*)d_ws + CNT_OFF);            // 1 KB
    unsigned short* idx   = (unsigned short*)((char*)d_ws + IDX_OFF); // 1 MB  (total ~2.05 MB)

    aux_kernel<<<320, 512, 0, stream>>>(W_hid, x, mids, wt, cnt16, idx, out);
    fbpinn_main<<<dim3(CHUNKS, NW), NTHR, 0, stream>>>(
        x, means, stds, mids, W_in, b_in, b_hid, W_out, b_out, wt, cnt16, idx, out);
}

// Round 15
// 141.371 us; speedup vs baseline: 1.0894x; 1.0894x over previous
//
#include <hip/hip_runtime.h>

#define NW    16
#define NEUR  128
#define NPTS  65536
#define SIGMA 0.02f
#define U_MEAN 0.0f
#define U_SD   1.0f
#define DELTA 0.17f          // cull radius: bound 2.1*11.4*e^-11.625 ~ 2.1e-4 (+1.2e-4 fp16) < 5.3e-4 thr

#define TILE   64           // points per block (4 waves x 16 rows)
#define NTHR   256
#define HPAD   136          // h2 row stride: 272B, 16B-aligned (R2: 132 -> misaligned-b128 replay)
#define MAT_HALVES 16384                  // frag-linear fp16 matrix: 128x128 (R10-verified layout)
#define WT_HALVES (2*NW*MAT_HALVES)       // 1,048,576 B
#define WT_BYTES (WT_HALVES*2)
#define CNT_OFF  WT_BYTES                 // 256 ints
#define IDX_OFF  (WT_BYTES + 1024)        // segmented u16 lists, 1 MB
#define NSEG   16
#define SEGPTS (NPTS/NSEG)
#define CAPSEG 2048                       // max fill ~1750 at DELTA=0.17
#define CHUNKS 512                        // 16*2048/64

typedef _Float16 half8 __attribute__((ext_vector_type(8)));
typedef float    f32x4 __attribute__((ext_vector_type(4)));

typedef const __attribute__((address_space(1))) void* gptr_t;
typedef       __attribute__((address_space(3))) void* lptr_t;

// R14 post-mortem: v_exp/v_rcp are near-full-rate on gfx950; paired-rcp tanh2
// ADDED VALU cycles (124K->135K/CU). tanh_fast's 6-instr form is the floor.
__device__ __forceinline__ float tanh_fast(float x) {
    float e = __expf(2.0f * x);
    return 1.0f - 2.0f * __builtin_amdgcn_rcpf(1.0f + e);
}

// ONE aux dispatch (R10's frag-linear prep, correctness-verified R10/R12/R13):
//   wt half offset = (s*8+c)*512 + lane*8 + j  holding W[e=c*16+m][d=s*32+q*8+j], lane=q*16+m
//   [0,32) prep | [32,288) bucket | [288,320) zero out[]
__global__ __launch_bounds__(512) void aux_kernel(
    const float* __restrict__ W_hid, const float* __restrict__ x,
    const float* __restrict__ mids,  _Float16* __restrict__ wt,
    int* __restrict__ cnt16, unsigned short* __restrict__ idx,
    float* __restrict__ out)
{
    const int b = blockIdx.x;
    const int t = threadIdx.x;

    if (b < 32) {                          // ---- prep: one 128x128 matrix per block
        __shared__ __align__(16) _Float16 tile[NEUR * HPAD];   // transpose staging
        const int lw = b;
        const float4* src = (const float4*)(W_hid + (size_t)lw * NEUR * NEUR);
#pragma unroll
        for (int it = 0; it < 8; ++it) {   // 4096 float4, coalesced over e
            int f4 = it * 512 + t;
            int d  = f4 >> 5;
            int e0 = (f4 & 31) << 2;
            float4 v = src[f4];
            tile[(e0 + 0) * HPAD + d] = (_Float16)v.x;
            tile[(e0 + 1) * HPAD + d] = (_Float16)v.y;
            tile[(e0 + 2) * HPAD + d] = (_Float16)v.z;
            tile[(e0 + 3) * HPAD + d] = (_Float16)v.w;
        }
        __syncthreads();
        half8* dst8 = (half8*)(wt + (size_t)lw * MAT_HALVES);  // 2048 half8 chunks
#pragma unroll
        for (int it = 0; it < 4; ++it) {
            int h8 = it * 512 + t;
            int sc = h8 >> 6;              // s*8+c
            int ln = h8 & 63;              // lane = q*16+m
            int s_ = sc >> 3, c_ = sc & 7;
            int q_ = ln >> 4, m_ = ln & 15;
            dst8[h8] = *(const half8*)&tile[(c_ * 16 + m_) * HPAD + s_ * 32 + q_ * 8];
        }
    } else if (b < 288) {                  // ---- bucket: (segment, window)
        const int s = (b - 32) & (NSEG - 1);
        const int w = (b - 32) >> 4;
        __shared__ int lcnt;
        if (t == 0) lcnt = 0;
        __syncthreads();
        const float lo = mids[w] - DELTA;
        const float hi = mids[w + 1] + DELTA;
        const int lane = t & 63;
        unsigned short* dst = idx + (size_t)(w * NSEG + s) * CAPSEG;
#pragma unroll
        for (int it = 0; it < SEGPTS / 512; ++it) {
            int i = s * SEGPTS + it * 512 + t;
            float xv = x[i];
            bool need = (xv >= lo) && (xv <= hi);
            unsigned long long mask = __ballot(need);
            if (mask) {
                int leader = (int)__builtin_ctzll(mask);
                int total  = (int)__popcll(mask);
                int rank   = (int)__popcll(mask & ((1ull << lane) - 1ull));
                int base = 0;
                if (lane == leader) base = atomicAdd(&lcnt, total);   // LDS atomic
                base = __shfl(base, leader);
                int slot = base + rank;
                if (need && slot < CAPSEG) dst[slot] = (unsigned short)i;
            }
        }
        __syncthreads();
        if (t == 0) cnt16[w * NSEG + s] = lcnt;
    } else {                               // ---- zero out[]
        int i4 = (b - 288) * 512 + t;
        float4 z = {0.f, 0.f, 0.f, 0.f};
        ((float4*)out)[i4] = z;
    }
}

__global__ __launch_bounds__(NTHR, 3) void fbpinn_main(
    const float* __restrict__ x,     const float* __restrict__ means,
    const float* __restrict__ stds,  const float* __restrict__ mids,
    const float* __restrict__ W_in,  const float* __restrict__ b_in,
    const float* __restrict__ b_hid, const float* __restrict__ W_out,
    const float* __restrict__ b_out, const _Float16* __restrict__ wt,
    const int* __restrict__ cnt16,   const unsigned short* __restrict__ idx,
    float* __restrict__ out)
{
    const int w    = blockIdx.y;
    const int base = blockIdx.x * TILE;

    // uniform scan of cnt16 (scalar loads); uniform exit
    int csh[NSEG];
    int total = 0;
#pragma unroll
    for (int k = 0; k < NSEG; ++k) {
        int c = cnt16[w * NSEG + k];
        c = c > CAPSEG ? CAPSEG : c;
        csh[k] = c;
        total += c;
    }
    if (base >= total) return;
    const int nvalid = min(TILE, total - base);

    __shared__ __align__(16) _Float16 Wb[MAT_HALVES];    // 32768 B, frag-linear (W0 then W1)
    __shared__ __align__(16) _Float16 Hl[TILE * HPAD];   // 17408 B (h2)

    const int t    = threadIdx.x;
    const int lane = t & 63;
    const int wave = t >> 6;           // 0..3
    const int m    = lane & 15;
    const int q    = lane >> 4;
    const int row0 = wave * 16;
    const int rsel = m & 3;

    // stage W0 via direct global->LDS (no VGPR round-trip — R12's register
    // prefetch spilled 207 MB to scratch)
    {
        const char* gb = (const char*)(wt + (size_t)(0 * NW + w) * MAT_HALVES) + t * 16;
        char*       lb = (char*)Wb + wave * 64 * 16;
#pragma unroll
        for (int i = 0; i < 8; ++i)
            __builtin_amdgcn_global_load_lds((gptr_t)(gb + i * 4096), (lptr_t)(lb + i * 4096), 16, 0, 0);
    }

    // per-thread gather of own point (row0+m); true-running-prefix scan (R7 fix)
    int v = base + min(row0 + m, nvalid - 1);
    int seg = 0, segbase = 0, pre = 0;
#pragma unroll
    for (int k = 0; k < NSEG - 1; ++k) {
        pre += csh[k];
        if (v >= pre) { seg = k + 1; segbase = pre; }
    }
    const int   gi = idx[(size_t)(w * NSEG + seg) * CAPSEG + (v - segbase)];
    const float xv = x[gi];

    // L0 into GEMM1 A-fragments (pre-barrier: depends only on own xv)
    const float xn = (xv - means[w]) * __builtin_amdgcn_rcpf(stds[w]);
    const float* win = W_in + w * NEUR;
    const float* bin = b_in + w * NEUR;
    half8 af[4];
#pragma unroll
    for (int s = 0; s < 4; ++s) {
        const int n0 = s * 32 + q * 8;
        float4 wv0 = *(const float4*)&win[n0];
        float4 wv1 = *(const float4*)&win[n0 + 4];
        float4 bv0 = *(const float4*)&bin[n0];
        float4 bv1 = *(const float4*)&bin[n0 + 4];
        af[s][0] = (_Float16)tanh_fast(fmaf(xn, wv0.x, bv0.x));
        af[s][1] = (_Float16)tanh_fast(fmaf(xn, wv0.y, bv0.y));
        af[s][2] = (_Float16)tanh_fast(fmaf(xn, wv0.z, bv0.z));
        af[s][3] = (_Float16)tanh_fast(fmaf(xn, wv0.w, bv0.w));
        af[s][4] = (_Float16)tanh_fast(fmaf(xn, wv1.x, bv1.x));
        af[s][5] = (_Float16)tanh_fast(fmaf(xn, wv1.y, bv1.y));
        af[s][6] = (_Float16)tanh_fast(fmaf(xn, wv1.z, bv1.z));
        af[s][7] = (_Float16)tanh_fast(fmaf(xn, wv1.w, bv1.w));
    }
    __syncthreads();   // barrier 1: W0 landed (vmcnt drained) + visible

    // GEMM1: B-frag (s,c) = contiguous 1 KB at Wb[(s*8+c)*512 halves]
    const half8* B = (const half8*)Wb;
    f32x4 acc[8];
    const f32x4 zz = {0.f, 0.f, 0.f, 0.f};
#pragma unroll
    for (int c = 0; c < 8; ++c) acc[c] = zz;
#pragma unroll
    for (int s = 0; s < 4; ++s)
#pragma unroll
        for (int c = 0; c < 8; ++c)
            acc[c] = __builtin_amdgcn_mfma_f32_16x16x32_f16(af[s], B[(s * 8 + c) * 64 + lane], acc[c], 0, 0, 0);

    __syncthreads();   // barrier 2: all waves done reading W0

    // issue W1 global->LDS now; latency hides under the h2-tanh block below
    {
        const char* gb = (const char*)(wt + (size_t)(1 * NW + w) * MAT_HALVES) + t * 16;
        char*       lb = (char*)Wb + wave * 64 * 16;
#pragma unroll
        for (int i = 0; i < 8; ++i)
            __builtin_amdgcn_global_load_lds((gptr_t)(gb + i * 4096), (lptr_t)(lb + i * 4096), 16, 0, 0);
    }

    // h2 = tanh(z2+b) -> Hl own rows (same-wave dep for GEMM2 A-reads — R11-verified)
    {
        const float* bh0 = b_hid + (0 * NW + w) * NEUR;
#pragma unroll
        for (int c = 0; c < 8; ++c) {
            float bb = bh0[c * 16 + m];
#pragma unroll
            for (int r = 0; r < 4; ++r)
                Hl[(row0 + q * 4 + r) * HPAD + c * 16 + m] = (_Float16)tanh_fast(acc[c][r] + bb);
        }
    }
    __syncthreads();   // barrier 3: W1 landed (vmcnt drained) + visible

    // GEMM2: A from own 16 rows of Hl, B frag-linear from Wb
#pragma unroll
    for (int c = 0; c < 8; ++c) acc[c] = zz;
#pragma unroll
    for (int s = 0; s < 4; ++s) {
        half8 a = *(const half8*)(Hl + (row0 + m) * HPAD + s * 32 + q * 8);
#pragma unroll
        for (int c = 0; c < 8; ++c)
            acc[c] = __builtin_amdgcn_mfma_f32_16x16x32_f16(a, B[(s * 8 + c) * 64 + lane], acc[c], 0, 0, 0);
    }

    // epilogue: h3 = tanh(z3+b); dot W_out (global, L1-hot); reduce over 16 m-lanes
    const float* bh1 = b_hid + (1 * NW + w) * NEUR;
    const float* wo  = W_out + w * NEUR;
    float t0 = 0.f, t1 = 0.f, t2 = 0.f, t3 = 0.f;
#pragma unroll
    for (int c = 0; c < 8; ++c) {
        float b  = bh1[c * 16 + m];
        float wc = wo[c * 16 + m];
        t0 = fmaf(tanh_fast(acc[c][0] + b), wc, t0);
        t1 = fmaf(tanh_fast(acc[c][1] + b), wc, t1);
        t2 = fmaf(tanh_fast(acc[c][2] + b), wc, t2);
        t3 = fmaf(tanh_fast(acc[c][3] + b), wc, t3);
    }
    t0 += __shfl_xor(t0, 1); t1 += __shfl_xor(t1, 1);
    t2 += __shfl_xor(t2, 1); t3 += __shfl_xor(t3, 1);
    t0 += __shfl_xor(t0, 2); t1 += __shfl_xor(t1, 2);
    t2 += __shfl_xor(t2, 2); t3 += __shfl_xor(t3, 2);
    float vsum = (rsel == 0) ? t0 : (rsel == 1) ? t1 : (rsel == 2) ? t2 : t3;
    vsum += __shfl_xor(vsum, 4);
    vsum += __shfl_xor(vsum, 8);

    // point data for slot = row0 + q*4 + rsel lives at lane 20*q + rsel (R12-verified)
    const int   slot  = row0 + q * 4 + rsel;
    const float xslot = __shfl(xv, 20 * q + rsel);
    const int   gslot = __shfl(gi, 20 * q + rsel);
    if (m < 4 && slot < nvalid) {
        float u   = (vsum + b_out[w]) * U_SD + U_MEAN;
        float xl  = (xslot - mids[w])     * (1.0f / SIGMA);
        float xr  = (xslot - mids[w + 1]) * (1.0f / SIGMA);
        float wf  = __builtin_amdgcn_rcpf(1.0f + __expf(xl)) *
                    __builtin_amdgcn_rcpf(1.0f + __expf(-xr));
        atomicAdd(&out[gslot], wf * u);
    }
}

extern "C" void kernel_launch(void* const* d_in, const int* in_sizes, int n_in,
                              void* d_out, int out_size, void* d_ws, size_t ws_size,
                              hipStream_t stream) {
    const float* x     = (const float*)d_in[0];
    const float* means = (const float*)d_in[1];
    const float* stds  = (const float*)d_in[2];
    const float* mids  = (const float*)d_in[3];
    const float* W_in  = (const float*)d_in[4];
    const float* b_in  = (const float*)d_in[5];
    const float* W_hid = (const float*)d_in[6];
    const float* b_hid = (const float*)d_in[7];
    const float* W_out = (const float*)d_in[8];
    const float* b_out = (const float*)d_in[9];
    float* out = (float*)d_out;

    _Float16*       wt    = (_Float16*)d_ws;                          // 1,048,576 B
    int*            cnt16 = (int*)((char*)d_ws + CNT_OFF);            // 1 KB
    unsigned short* idx   = (unsigned short*)((char*)d_ws + IDX_OFF); // 1 MB  (total ~2.05 MB)

    aux_kernel<<<320, 512, 0, stream>>>(W_hid, x, mids, wt, cnt16, idx, out);
    fbpinn_main<<<dim3(CHUNKS, NW), NTHR, 0, stream>>>(
        x, means, stds, mids, W_in, b_in, b_hid, W_out, b_out, wt, cnt16, idx, out);
}

// Round 16
// 135.627 us; speedup vs baseline: 1.1356x; 1.0423x over previous
//
#include <hip/hip_runtime.h>

#define NW    16
#define NEUR  128
#define NPTS  65536
#define SIGMA 0.02f
#define U_MEAN 0.0f
#define U_SD   1.0f
#define DELTA 0.15f          // cull radius; error base invisible at 0.17 (absmax bit-identical), x2.7 still < fp16 floor

#define TILE   64           // points per block (4 waves x 16 rows)
#define NTHR   256
#define HPAD   136          // h2 row stride: 272B, 16B-aligned (R2: 132 -> misaligned-b128 replay)
#define MAT_HALVES 16384                  // frag-linear fp16 matrix: 128x128 (R10-verified layout)
#define WT_HALVES (2*NW*MAT_HALVES)       // 1,048,576 B
#define WT_BYTES (WT_HALVES*2)
#define CNT_OFF  WT_BYTES                 // 256 ints
#define IDX_OFF  (WT_BYTES + 1024)        // segmented u16 lists, 1 MB
#define BIAS_OFF (IDX_OFF + NW*16*2048*2) // 6144 floats: [0,2048)=2*b_in, [2048,6144)=2*b_hid
#define NSEG   16
#define SEGPTS (NPTS/NSEG)
#define CAPSEG 2048                       // max fill ~1560 at DELTA=0.15
#define CHUNKS 512

typedef _Float16 half8 __attribute__((ext_vector_type(8)));
typedef float    f32x4 __attribute__((ext_vector_type(4)));

typedef const __attribute__((address_space(1))) void* gptr_t;
typedef       __attribute__((address_space(3))) void* lptr_t;

// Pre-scaled tanh: caller passes y = 2x (folded into weights/biases: wt=2W,
// bias2=2b, xn doubled). 5 VALU instead of 6 (R14: exp/rcp are full-rate; the
// instruction COUNT is the floor, so drop one mul per tanh).
__device__ __forceinline__ float tanh_pre(float y) {
    float e = __expf(y);
    return 1.0f - 2.0f * __builtin_amdgcn_rcpf(1.0f + e);
}

// ONE aux dispatch:
//   [0,32)    prep: wt = 2*W_hid in frag-linear layout (R10-verified):
//             half offset (s*8+c)*512 + lane*8 + j = W[e=c*16+m][d=s*32+q*8+j], lane=q*16+m
//   [32,288)  bucket: segment s of window w -> compacted u16 list + cnt16
//   [288,320) zero out[]; block 288 also writes bias2 = 2*{b_in, b_hid}
__global__ __launch_bounds__(512) void aux_kernel(
    const float* __restrict__ W_hid, const float* __restrict__ x,
    const float* __restrict__ mids,  const float* __restrict__ b_in,
    const float* __restrict__ b_hid, _Float16* __restrict__ wt,
    int* __restrict__ cnt16, unsigned short* __restrict__ idx,
    float* __restrict__ bias2, float* __restrict__ out)
{
    const int b = blockIdx.x;
    const int t = threadIdx.x;

    if (b < 32) {                          // ---- prep: one 128x128 matrix per block
        __shared__ __align__(16) _Float16 tile[NEUR * HPAD];   // transpose staging
        const int lw = b;
        const float4* src = (const float4*)(W_hid + (size_t)lw * NEUR * NEUR);
#pragma unroll
        for (int it = 0; it < 8; ++it) {   // 4096 float4, coalesced over e
            int f4 = it * 512 + t;
            int d  = f4 >> 5;
            int e0 = (f4 & 31) << 2;
            float4 v = src[f4];
            tile[(e0 + 0) * HPAD + d] = (_Float16)(2.0f * v.x);   // x2 prescale (exact)
            tile[(e0 + 1) * HPAD + d] = (_Float16)(2.0f * v.y);
            tile[(e0 + 2) * HPAD + d] = (_Float16)(2.0f * v.z);
            tile[(e0 + 3) * HPAD + d] = (_Float16)(2.0f * v.w);
        }
        __syncthreads();
        half8* dst8 = (half8*)(wt + (size_t)lw * MAT_HALVES);  // 2048 half8 chunks
#pragma unroll
        for (int it = 0; it < 4; ++it) {
            int h8 = it * 512 + t;
            int sc = h8 >> 6;              // s*8+c
            int ln = h8 & 63;              // lane = q*16+m
            int s_ = sc >> 3, c_ = sc & 7;
            int q_ = ln >> 4, m_ = ln & 15;
            dst8[h8] = *(const half8*)&tile[(c_ * 16 + m_) * HPAD + s_ * 32 + q_ * 8];
        }
    } else if (b < 288) {                  // ---- bucket: (segment, window)
        const int s = (b - 32) & (NSEG - 1);
        const int w = (b - 32) >> 4;
        __shared__ int lcnt;
        if (t == 0) lcnt = 0;
        __syncthreads();
        const float lo = mids[w] - DELTA;
        const float hi = mids[w + 1] + DELTA;
        const int lane = t & 63;
        unsigned short* dst = idx + (size_t)(w * NSEG + s) * CAPSEG;
#pragma unroll
        for (int it = 0; it < SEGPTS / 512; ++it) {
            int i = s * SEGPTS + it * 512 + t;
            float xv = x[i];
            bool need = (xv >= lo) && (xv <= hi);
            unsigned long long mask = __ballot(need);
            if (mask) {
                int leader = (int)__builtin_ctzll(mask);
                int total  = (int)__popcll(mask);
                int rank   = (int)__popcll(mask & ((1ull << lane) - 1ull));
                int base = 0;
                if (lane == leader) base = atomicAdd(&lcnt, total);   // LDS atomic
                base = __shfl(base, leader);
                int slot = base + rank;
                if (need && slot < CAPSEG) dst[slot] = (unsigned short)i;
            }
        }
        __syncthreads();
        if (t == 0) cnt16[w * NSEG + s] = lcnt;
    } else {                               // ---- zero out[]; bias prescale in block 288
        int i4 = (b - 288) * 512 + t;
        float4 z = {0.f, 0.f, 0.f, 0.f};
        ((float4*)out)[i4] = z;
        if (b == 288) {
#pragma unroll
            for (int i = t; i < 6144; i += 512) {
                float v = (i < 2048) ? b_in[i] : b_hid[i - 2048];
                bias2[i] = 2.0f * v;
            }
        }
    }
}

__global__ __launch_bounds__(NTHR, 3) void fbpinn_main(
    const float* __restrict__ x,     const float* __restrict__ means,
    const float* __restrict__ stds,  const float* __restrict__ mids,
    const float* __restrict__ W_in,  const float* __restrict__ bias2,
    const float* __restrict__ W_out, const float* __restrict__ b_out,
    const _Float16* __restrict__ wt, const int* __restrict__ cnt16,
    const unsigned short* __restrict__ idx, float* __restrict__ out)
{
    const int w    = blockIdx.y;
    const int base = blockIdx.x * TILE;

    // uniform scan of cnt16 (scalar loads); uniform exit
    int csh[NSEG];
    int total = 0;
#pragma unroll
    for (int k = 0; k < NSEG; ++k) {
        int c = cnt16[w * NSEG + k];
        c = c > CAPSEG ? CAPSEG : c;
        csh[k] = c;
        total += c;
    }
    if (base >= total) return;
    const int nvalid = min(TILE, total - base);

    __shared__ __align__(16) _Float16 Wb[MAT_HALVES];    // 32768 B, frag-linear (2W0 then 2W1)
    __shared__ __align__(16) _Float16 Hl[TILE * HPAD];   // 17408 B (h2)

    const int t    = threadIdx.x;
    const int lane = t & 63;
    const int wave = t >> 6;           // 0..3
    const int m    = lane & 15;
    const int q    = lane >> 4;
    const int row0 = wave * 16;
    const int rsel = m & 3;

    // stage 2*W0 via direct global->LDS (R12: register prefetch spills; this doesn't)
    {
        const char* gb = (const char*)(wt + (size_t)(0 * NW + w) * MAT_HALVES) + t * 16;
        char*       lb = (char*)Wb + wave * 64 * 16;
#pragma unroll
        for (int i = 0; i < 8; ++i)
            __builtin_amdgcn_global_load_lds((gptr_t)(gb + i * 4096), (lptr_t)(lb + i * 4096), 16, 0, 0);
    }

    // per-thread gather of own point (row0+m); true-running-prefix scan (R7 fix)
    int v = base + min(row0 + m, nvalid - 1);
    int seg = 0, segbase = 0, pre = 0;
#pragma unroll
    for (int k = 0; k < NSEG - 1; ++k) {
        pre += csh[k];
        if (v >= pre) { seg = k + 1; segbase = pre; }
    }
    const int   gi = idx[(size_t)(w * NSEG + seg) * CAPSEG + (v - segbase)];
    const float xv = x[gi];

    // L0 into GEMM1 A-fragments; xn doubled so tanh args arrive pre-scaled
    const float xn = 2.0f * (xv - means[w]) * __builtin_amdgcn_rcpf(stds[w]);
    const float* win  = W_in + w * NEUR;
    const float* bin2 = bias2 + w * NEUR;              // 2*b_in
    half8 af[4];
#pragma unroll
    for (int s = 0; s < 4; ++s) {
        const int n0 = s * 32 + q * 8;
        float4 wv0 = *(const float4*)&win[n0];
        float4 wv1 = *(const float4*)&win[n0 + 4];
        float4 bv0 = *(const float4*)&bin2[n0];
        float4 bv1 = *(const float4*)&bin2[n0 + 4];
        af[s][0] = (_Float16)tanh_pre(fmaf(xn, wv0.x, bv0.x));
        af[s][1] = (_Float16)tanh_pre(fmaf(xn, wv0.y, bv0.y));
        af[s][2] = (_Float16)tanh_pre(fmaf(xn, wv0.z, bv0.z));
        af[s][3] = (_Float16)tanh_pre(fmaf(xn, wv0.w, bv0.w));
        af[s][4] = (_Float16)tanh_pre(fmaf(xn, wv1.x, bv1.x));
        af[s][5] = (_Float16)tanh_pre(fmaf(xn, wv1.y, bv1.y));
        af[s][6] = (_Float16)tanh_pre(fmaf(xn, wv1.z, bv1.z));
        af[s][7] = (_Float16)tanh_pre(fmaf(xn, wv1.w, bv1.w));
    }
    __syncthreads();   // barrier 1: W0 landed (vmcnt drained) + visible

    // GEMM1: acc = h1 @ (2W0)^T = 2*z2 (B-frag (s,c) = contiguous 1 KB)
    const half8* B = (const half8*)Wb;
    f32x4 acc[8];
    const f32x4 zz = {0.f, 0.f, 0.f, 0.f};
#pragma unroll
    for (int c = 0; c < 8; ++c) acc[c] = zz;
#pragma unroll
    for (int s = 0; s < 4; ++s)
#pragma unroll
        for (int c = 0; c < 8; ++c)
            acc[c] = __builtin_amdgcn_mfma_f32_16x16x32_f16(af[s], B[(s * 8 + c) * 64 + lane], acc[c], 0, 0, 0);

    __syncthreads();   // barrier 2: all waves done reading W0

    // issue 2*W1 global->LDS now; latency hides under the h2-tanh block below
    {
        const char* gb = (const char*)(wt + (size_t)(1 * NW + w) * MAT_HALVES) + t * 16;
        char*       lb = (char*)Wb + wave * 64 * 16;
#pragma unroll
        for (int i = 0; i < 8; ++i)
            __builtin_amdgcn_global_load_lds((gptr_t)(gb + i * 4096), (lptr_t)(lb + i * 4096), 16, 0, 0);
    }

    // h2 = tanh(z2+b) = tanh_pre(2z2 + 2b) -> Hl own rows (same-wave dep for GEMM2 A-reads)
    {
        const float* bh0 = bias2 + 2048 + w * NEUR;    // 2*b_hid[0]
#pragma unroll
        for (int c = 0; c < 8; ++c) {
            float bb = bh0[c * 16 + m];
#pragma unroll
            for (int r = 0; r < 4; ++r)
                Hl[(row0 + q * 4 + r) * HPAD + c * 16 + m] = (_Float16)tanh_pre(acc[c][r] + bb);
        }
    }
    __syncthreads();   // barrier 3: W1 landed (vmcnt drained) + visible

    // GEMM2: acc = h2 @ (2W1)^T = 2*z3
#pragma unroll
    for (int c = 0; c < 8; ++c) acc[c] = zz;
#pragma unroll
    for (int s = 0; s < 4; ++s) {
        half8 a = *(const half8*)(Hl + (row0 + m) * HPAD + s * 32 + q * 8);
#pragma unroll
        for (int c = 0; c < 8; ++c)
            acc[c] = __builtin_amdgcn_mfma_f32_16x16x32_f16(a, B[(s * 8 + c) * 64 + lane], acc[c], 0, 0, 0);
    }

    // epilogue: h3 = tanh_pre(2z3 + 2b); dot W_out; reduce over 16 m-lanes
    const float* bh1 = bias2 + 2048 + (NW + w) * NEUR; // 2*b_hid[1]
    const float* wo  = W_out + w * NEUR;
    float t0 = 0.f, t1 = 0.f, t2 = 0.f, t3 = 0.f;
#pragma unroll
    for (int c = 0; c < 8; ++c) {
        float b  = bh1[c * 16 + m];
        float wc = wo[c * 16 + m];
        t0 = fmaf(tanh_pre(acc[c][0] + b), wc, t0);
        t1 = fmaf(tanh_pre(acc[c][1] + b), wc, t1);
        t2 = fmaf(tanh_pre(acc[c][2] + b), wc, t2);
        t3 = fmaf(tanh_pre(acc[c][3] + b), wc, t3);
    }
    t0 += __shfl_xor(t0, 1); t1 += __shfl_xor(t1, 1);
    t2 += __shfl_xor(t2, 1); t3 += __shfl_xor(t3, 1);
    t0 += __shfl_xor(t0, 2); t1 += __shfl_xor(t1, 2);
    t2 += __shfl_xor(t2, 2); t3 += __shfl_xor(t3, 2);
    float vsum = (rsel == 0) ? t0 : (rsel == 1) ? t1 : (rsel == 2) ? t2 : t3;
    vsum += __shfl_xor(vsum, 4);
    vsum += __shfl_xor(vsum, 8);

    // point data for slot = row0 + q*4 + rsel lives at lane 20*q + rsel (R12-verified)
    const int   slot  = row0 + q * 4 + rsel;
    const float xslot = __shfl(xv, 20 * q + rsel);
    const int   gslot = __shfl(gi, 20 * q + rsel);
    if (m < 4 && slot < nvalid) {
        float u   = (vsum + b_out[w]) * U_SD + U_MEAN;
        float xl  = (xslot - mids[w])     * (1.0f / SIGMA);
        float xr  = (xslot - mids[w + 1]) * (1.0f / SIGMA);
        float wf  = __builtin_amdgcn_rcpf(1.0f + __expf(xl)) *
                    __builtin_amdgcn_rcpf(1.0f + __expf(-xr));
        atomicAdd(&out[gslot], wf * u);
    }
}

extern "C" void kernel_launch(void* const* d_in, const int* in_sizes, int n_in,
                              void* d_out, int out_size, void* d_ws, size_t ws_size,
                              hipStream_t stream) {
    const float* x     = (const float*)d_in[0];
    const float* means = (const float*)d_in[1];
    const float* stds  = (const float*)d_in[2];
    const float* mids  = (const float*)d_in[3];
    const float* W_in  = (const float*)d_in[4];
    const float* b_in  = (const float*)d_in[5];
    const float* W_hid = (const float*)d_in[6];
    const float* b_hid = (const float*)d_in[7];
    const float* W_out = (const float*)d_in[8];
    const float* b_out = (const float*)d_in[9];
    float* out = (float*)d_out;

    _Float16*       wt    = (_Float16*)d_ws;                           // 1,048,576 B
    int*            cnt16 = (int*)((char*)d_ws + CNT_OFF);             // 1 KB
    unsigned short* idx   = (unsigned short*)((char*)d_ws + IDX_OFF);  // 1 MB
    float*          bias2 = (float*)((char*)d_ws + BIAS_OFF);          // 24 KB (total ~2.12 MB)

    aux_kernel<<<320, 512, 0, stream>>>(W_hid, x, mids, b_in, b_hid, wt, cnt16, idx, bias2, out);
    fbpinn_main<<<dim3(CHUNKS, NW), NTHR, 0, stream>>>(
        x, means, stds, mids, W_in, bias2, W_out, b_out, wt, cnt16, idx, out);
}

// Round 17
// 132.723 us; speedup vs baseline: 1.1604x; 1.0219x over previous
//
#include <hip/hip_runtime.h>

#define NW    16
#define NEUR  128
#define NPTS  65536
#define SIGMA 0.02f
#define U_MEAN 0.0f
#define U_SD   1.0f
#define DELTA 0.15f          // cull radius; measured absmax bit-identical 0.19->0.15

#define SCALE2L 2.8853900817779268f   // 2*log2(e): folds BOTH the tanh 2x and exp->exp2 mul
#define WINK    72.13475204444817f    // log2(e)/SIGMA for window exp2

#define TILE   64           // points per block (4 waves x 16 rows)
#define NTHR   256
#define HPAD   136          // h2 row stride: 272B, 16B-aligned (R2: 132 -> misaligned-b128 replay)
#define MAT_HALVES 16384                  // frag-linear fp16 matrix: 128x128 (R10-verified layout)
#define WT_HALVES (2*NW*MAT_HALVES)       // 1,048,576 B
#define WT_BYTES (WT_HALVES*2)
#define CNT_OFF  WT_BYTES                 // 256 ints
#define IDX_OFF  (WT_BYTES + 1024)        // segmented u16 lists, 1 MB
#define BIAS_OFF (IDX_OFF + NW*16*2048*2) // 6144 floats: [0,2048)=s*b_in, [2048,6144)=s*b_hid
#define NSEG   16
#define SEGPTS (NPTS/NSEG)
#define CAPSEG 2048                       // max fill ~1560 at DELTA=0.15
#define CHUNKS 512

typedef _Float16 half8 __attribute__((ext_vector_type(8)));
typedef float    f32x4 __attribute__((ext_vector_type(4)));

typedef const __attribute__((address_space(1))) void* gptr_t;
typedef       __attribute__((address_space(3))) void* lptr_t;

// 4-instr tanh: caller passes y = 2*log2(e)*x (scale folded into weights/
// biases/xn). R16 audit: __expf = v_mul(log2e) + v_exp since v_exp_f32 is 2^x;
// calling exp2 on the pre-scaled arg removes that hidden mul.
// exp2 -> +inf => rcp=0 => 1.0; -> 0 => rcp(1)=1 => -1.0: saturation exact.
__device__ __forceinline__ float tanh_pre(float y) {
    float e = __builtin_amdgcn_exp2f(y);
    return 1.0f - 2.0f * __builtin_amdgcn_rcpf(1.0f + e);
}

// ONE aux dispatch:
//   [0,32)    prep: wt = SCALE2L*W_hid in frag-linear layout (R10-verified):
//             half offset (s*8+c)*512 + lane*8 + j = W[e=c*16+m][d=s*32+q*8+j], lane=q*16+m
//   [32,288)  bucket: segment s of window w -> compacted u16 list + cnt16
//   [288,320) zero out[]; block 288 also writes bias2 = SCALE2L*{b_in, b_hid}
__global__ __launch_bounds__(512) void aux_kernel(
    const float* __restrict__ W_hid, const float* __restrict__ x,
    const float* __restrict__ mids,  const float* __restrict__ b_in,
    const float* __restrict__ b_hid, _Float16* __restrict__ wt,
    int* __restrict__ cnt16, unsigned short* __restrict__ idx,
    float* __restrict__ bias2, float* __restrict__ out)
{
    const int b = blockIdx.x;
    const int t = threadIdx.x;

    if (b < 32) {                          // ---- prep: one 128x128 matrix per block
        __shared__ __align__(16) _Float16 tile[NEUR * HPAD];   // transpose staging
        const int lw = b;
        const float4* src = (const float4*)(W_hid + (size_t)lw * NEUR * NEUR);
#pragma unroll
        for (int it = 0; it < 8; ++it) {   // 4096 float4, coalesced over e
            int f4 = it * 512 + t;
            int d  = f4 >> 5;
            int e0 = (f4 & 31) << 2;
            float4 v = src[f4];
            tile[(e0 + 0) * HPAD + d] = (_Float16)(SCALE2L * v.x);
            tile[(e0 + 1) * HPAD + d] = (_Float16)(SCALE2L * v.y);
            tile[(e0 + 2) * HPAD + d] = (_Float16)(SCALE2L * v.z);
            tile[(e0 + 3) * HPAD + d] = (_Float16)(SCALE2L * v.w);
        }
        __syncthreads();
        half8* dst8 = (half8*)(wt + (size_t)lw * MAT_HALVES);  // 2048 half8 chunks
#pragma unroll
        for (int it = 0; it < 4; ++it) {
            int h8 = it * 512 + t;
            int sc = h8 >> 6;              // s*8+c
            int ln = h8 & 63;              // lane = q*16+m
            int s_ = sc >> 3, c_ = sc & 7;
            int q_ = ln >> 4, m_ = ln & 15;
            dst8[h8] = *(const half8*)&tile[(c_ * 16 + m_) * HPAD + s_ * 32 + q_ * 8];
        }
    } else if (b < 288) {                  // ---- bucket: (segment, window)
        const int s = (b - 32) & (NSEG - 1);
        const int w = (b - 32) >> 4;
        __shared__ int lcnt;
        if (t == 0) lcnt = 0;
        __syncthreads();
        const float lo = mids[w] - DELTA;
        const float hi = mids[w + 1] + DELTA;
        const int lane = t & 63;
        unsigned short* dst = idx + (size_t)(w * NSEG + s) * CAPSEG;
#pragma unroll
        for (int it = 0; it < SEGPTS / 512; ++it) {
            int i = s * SEGPTS + it * 512 + t;
            float xv = x[i];
            bool need = (xv >= lo) && (xv <= hi);
            unsigned long long mask = __ballot(need);
            if (mask) {
                int leader = (int)__builtin_ctzll(mask);
                int total  = (int)__popcll(mask);
                int rank   = (int)__popcll(mask & ((1ull << lane) - 1ull));
                int base = 0;
                if (lane == leader) base = atomicAdd(&lcnt, total);   // LDS atomic
                base = __shfl(base, leader);
                int slot = base + rank;
                if (need && slot < CAPSEG) dst[slot] = (unsigned short)i;
            }
        }
        __syncthreads();
        if (t == 0) cnt16[w * NSEG + s] = lcnt;
    } else {                               // ---- zero out[]; bias prescale in block 288
        int i4 = (b - 288) * 512 + t;
        float4 z = {0.f, 0.f, 0.f, 0.f};
        ((float4*)out)[i4] = z;
        if (b == 288) {
#pragma unroll
            for (int i = t; i < 6144; i += 512) {
                float v = (i < 2048) ? b_in[i] : b_hid[i - 2048];
                bias2[i] = SCALE2L * v;
            }
        }
    }
}

__global__ __launch_bounds__(NTHR, 3) void fbpinn_main(
    const float* __restrict__ x,     const float* __restrict__ means,
    const float* __restrict__ stds,  const float* __restrict__ mids,
    const float* __restrict__ W_in,  const float* __restrict__ bias2,
    const float* __restrict__ W_out, const float* __restrict__ b_out,
    const _Float16* __restrict__ wt, const int* __restrict__ cnt16,
    const unsigned short* __restrict__ idx, float* __restrict__ out)
{
    const int w    = blockIdx.y;
    const int base = blockIdx.x * TILE;

    // uniform scan of cnt16 (scalar loads); uniform exit
    int csh[NSEG];
    int total = 0;
#pragma unroll
    for (int k = 0; k < NSEG; ++k) {
        int c = cnt16[w * NSEG + k];
        c = c > CAPSEG ? CAPSEG : c;
        csh[k] = c;
        total += c;
    }
    if (base >= total) return;
    const int nvalid = min(TILE, total - base);

    __shared__ __align__(16) _Float16 Wb[MAT_HALVES];    // 32768 B, frag-linear (sW0 then sW1)
    __shared__ __align__(16) _Float16 Hl[TILE * HPAD];   // 17408 B (h2)

    const int t    = threadIdx.x;
    const int lane = t & 63;
    const int wave = t >> 6;           // 0..3
    const int m    = lane & 15;
    const int q    = lane >> 4;
    const int row0 = wave * 16;
    const int rsel = m & 3;

    // stage s*W0 via direct global->LDS (R12: register prefetch spills; this doesn't)
    {
        const char* gb = (const char*)(wt + (size_t)(0 * NW + w) * MAT_HALVES) + t * 16;
        char*       lb = (char*)Wb + wave * 64 * 16;
#pragma unroll
        for (int i = 0; i < 8; ++i)
            __builtin_amdgcn_global_load_lds((gptr_t)(gb + i * 4096), (lptr_t)(lb + i * 4096), 16, 0, 0);
    }

    // per-thread gather of own point (row0+m); true-running-prefix scan (R7 fix)
    int v = base + min(row0 + m, nvalid - 1);
    int seg = 0, segbase = 0, pre = 0;
#pragma unroll
    for (int k = 0; k < NSEG - 1; ++k) {
        pre += csh[k];
        if (v >= pre) { seg = k + 1; segbase = pre; }
    }
    const int   gi = idx[(size_t)(w * NSEG + seg) * CAPSEG + (v - segbase)];
    const float xv = x[gi];

    // L0 into GEMM1 A-fragments; xn carries the full 2*log2e prescale
    const float xn = SCALE2L * (xv - means[w]) * __builtin_amdgcn_rcpf(stds[w]);
    const float* win  = W_in + w * NEUR;
    const float* bin2 = bias2 + w * NEUR;              // s*b_in
    half8 af[4];
#pragma unroll
    for (int s = 0; s < 4; ++s) {
        const int n0 = s * 32 + q * 8;
        float4 wv0 = *(const float4*)&win[n0];
        float4 wv1 = *(const float4*)&win[n0 + 4];
        float4 bv0 = *(const float4*)&bin2[n0];
        float4 bv1 = *(const float4*)&bin2[n0 + 4];
        af[s][0] = (_Float16)tanh_pre(fmaf(xn, wv0.x, bv0.x));
        af[s][1] = (_Float16)tanh_pre(fmaf(xn, wv0.y, bv0.y));
        af[s][2] = (_Float16)tanh_pre(fmaf(xn, wv0.z, bv0.z));
        af[s][3] = (_Float16)tanh_pre(fmaf(xn, wv0.w, bv0.w));
        af[s][4] = (_Float16)tanh_pre(fmaf(xn, wv1.x, bv1.x));
        af[s][5] = (_Float16)tanh_pre(fmaf(xn, wv1.y, bv1.y));
        af[s][6] = (_Float16)tanh_pre(fmaf(xn, wv1.z, bv1.z));
        af[s][7] = (_Float16)tanh_pre(fmaf(xn, wv1.w, bv1.w));
    }
    __syncthreads();   // barrier 1: W0 landed (vmcnt drained) + visible

    // GEMM1: acc = h1 @ (sW0)^T = s*z2 (B-frag (s,c) = contiguous 1 KB)
    const half8* B = (const half8*)Wb;
    f32x4 acc[8];
    const f32x4 zz = {0.f, 0.f, 0.f, 0.f};
#pragma unroll
    for (int c = 0; c < 8; ++c) acc[c] = zz;
#pragma unroll
    for (int s = 0; s < 4; ++s)
#pragma unroll
        for (int c = 0; c < 8; ++c)
            acc[c] = __builtin_amdgcn_mfma_f32_16x16x32_f16(af[s], B[(s * 8 + c) * 64 + lane], acc[c], 0, 0, 0);

    __syncthreads();   // barrier 2: all waves done reading W0

    // issue s*W1 global->LDS now; latency hides under the h2-tanh block below
    {
        const char* gb = (const char*)(wt + (size_t)(1 * NW + w) * MAT_HALVES) + t * 16;
        char*       lb = (char*)Wb + wave * 64 * 16;
#pragma unroll
        for (int i = 0; i < 8; ++i)
            __builtin_amdgcn_global_load_lds((gptr_t)(gb + i * 4096), (lptr_t)(lb + i * 4096), 16, 0, 0);
    }

    // h2 = tanh_pre(s*z2 + s*b) -> Hl own rows (same-wave dep for GEMM2 A-reads)
    {
        const float* bh0 = bias2 + 2048 + w * NEUR;    // s*b_hid[0]
#pragma unroll
        for (int c = 0; c < 8; ++c) {
            float bb = bh0[c * 16 + m];
#pragma unroll
            for (int r = 0; r < 4; ++r)
                Hl[(row0 + q * 4 + r) * HPAD + c * 16 + m] = (_Float16)tanh_pre(acc[c][r] + bb);
        }
    }
    __syncthreads();   // barrier 3: W1 landed (vmcnt drained) + visible

    // GEMM2: acc = h2 @ (sW1)^T = s*z3
#pragma unroll
    for (int c = 0; c < 8; ++c) acc[c] = zz;
#pragma unroll
    for (int s = 0; s < 4; ++s) {
        half8 a = *(const half8*)(Hl + (row0 + m) * HPAD + s * 32 + q * 8);
#pragma unroll
        for (int c = 0; c < 8; ++c)
            acc[c] = __builtin_amdgcn_mfma_f32_16x16x32_f16(a, B[(s * 8 + c) * 64 + lane], acc[c], 0, 0, 0);
    }

    // epilogue: h3 = tanh_pre(s*z3 + s*b); dot W_out; reduce over 16 m-lanes
    const float* bh1 = bias2 + 2048 + (NW + w) * NEUR; // s*b_hid[1]
    const float* wo  = W_out + w * NEUR;
    float t0 = 0.f, t1 = 0.f, t2 = 0.f, t3 = 0.f;
#pragma unroll
    for (int c = 0; c < 8; ++c) {
        float b  = bh1[c * 16 + m];
        float wc = wo[c * 16 + m];
        t0 = fmaf(tanh_pre(acc[c][0] + b), wc, t0);
        t1 = fmaf(tanh_pre(acc[c][1] + b), wc, t1);
        t2 = fmaf(tanh_pre(acc[c][2] + b), wc, t2);
        t3 = fmaf(tanh_pre(acc[c][3] + b), wc, t3);
    }
    t0 += __shfl_xor(t0, 1); t1 += __shfl_xor(t1, 1);
    t2 += __shfl_xor(t2, 1); t3 += __shfl_xor(t3, 1);
    t0 += __shfl_xor(t0, 2); t1 += __shfl_xor(t1, 2);
    t2 += __shfl_xor(t2, 2); t3 += __shfl_xor(t3, 2);
    float vsum = (rsel == 0) ? t0 : (rsel == 1) ? t1 : (rsel == 2) ? t2 : t3;
    vsum += __shfl_xor(vsum, 4);
    vsum += __shfl_xor(vsum, 8);

    // point data for slot = row0 + q*4 + rsel lives at lane 20*q + rsel (R12-verified)
    const int   slot  = row0 + q * 4 + rsel;
    const float xslot = __shfl(xv, 20 * q + rsel);
    const int   gslot = __shfl(gi, 20 * q + rsel);
    if (m < 4 && slot < nvalid) {
        float u   = (vsum + b_out[w]) * U_SD + U_MEAN;
        // wf = sigmoid(-xl)*sigmoid(xr); exp via exp2 with K = log2e/sigma
        float xl2 = (xslot - mids[w])     * WINK;
        float xr2 = (xslot - mids[w + 1]) * WINK;
        float wf  = __builtin_amdgcn_rcpf(1.0f + __builtin_amdgcn_exp2f(xl2)) *
                    __builtin_amdgcn_rcpf(1.0f + __builtin_amdgcn_exp2f(-xr2));
        atomicAdd(&out[gslot], wf * u);
    }
}

extern "C" void kernel_launch(void* const* d_in, const int* in_sizes, int n_in,
                              void* d_out, int out_size, void* d_ws, size_t ws_size,
                              hipStream_t stream) {
    const float* x     = (const float*)d_in[0];
    const float* means = (const float*)d_in[1];
    const float* stds  = (const float*)d_in[2];
    const float* mids  = (const float*)d_in[3];
    const float* W_in  = (const float*)d_in[4];
    const float* b_in  = (const float*)d_in[5];
    const float* W_hid = (const float*)d_in[6];
    const float* b_hid = (const float*)d_in[7];
    const float* W_out = (const float*)d_in[8];
    const float* b_out = (const float*)d_in[9];
    float* out = (float*)d_out;

    _Float16*       wt    = (_Float16*)d_ws;                           // 1,048,576 B
    int*            cnt16 = (int*)((char*)d_ws + CNT_OFF);             // 1 KB
    unsigned short* idx   = (unsigned short*)((char*)d_ws + IDX_OFF);  // 1 MB
    float*          bias2 = (float*)((char*)d_ws + BIAS_OFF);          // 24 KB (total ~2.12 MB)

    aux_kernel<<<320, 512, 0, stream>>>(W_hid, x, mids, b_in, b_hid, wt, cnt16, idx, bias2, out);
    fbpinn_main<<<dim3(CHUNKS, NW), NTHR, 0, stream>>>(
        x, means, stds, mids, W_in, bias2, W_out, b_out, wt, cnt16, idx, out);
}